// Round 1
// baseline (6900.825 us; speedup 1.0000x reference)
//
#include <hip/hip_runtime.h>

#define DD 16
#define HH 128
#define WW 128
#define DHW (DD * HH * WW)   // 262144
#define CIN 16
#define COUT 32
#define KK 27                // 3*3*3 taps

// ---------------------------------------------------------------------------
// Transpose x from [ci][z][y][x] to [z][y][x][ci] so that all 16 channels of a
// voxel are contiguous (enables float4 loads in the fused kernel).
// ---------------------------------------------------------------------------
__global__ __launch_bounds__(256) void transpose_x(const float* __restrict__ x,
                                                   float* __restrict__ xt) {
    int idx = blockIdx.x * 256 + threadIdx.x;      // over CIN*DHW, input order
    if (idx >= CIN * DHW) return;
    int ci = idx >> 18;            // DHW = 2^18
    int v  = idx & (DHW - 1);
    xt[(size_t)v * CIN + ci] = x[idx];
}

__device__ __forceinline__ void load16(const float* p, float* cv) {
    const float4* q = reinterpret_cast<const float4*>(p);
    float4 a = q[0], b = q[1], c = q[2], d = q[3];
    cv[0] = a.x; cv[1] = a.y; cv[2]  = a.z; cv[3]  = a.w;
    cv[4] = b.x; cv[5] = b.y; cv[6]  = b.z; cv[7]  = b.w;
    cv[8] = c.x; cv[9] = c.y; cv[10] = c.z; cv[11] = c.w;
    cv[12] = d.x; cv[13] = d.y; cv[14] = d.z; cv[15] = d.w;
}

// ---------------------------------------------------------------------------
// Fully fused deformable conv3d: one thread per output voxel.
// TR=true: x is channel-minor [z][y][x][ci]; TR=false: original [ci][z][y][x].
// ---------------------------------------------------------------------------
template <bool TR>
__global__ __launch_bounds__(128) void deform_fused(
    const float* __restrict__ x,
    const float* __restrict__ weight,   // [32][16][27]
    const float* __restrict__ bias,     // [32]
    const float* __restrict__ off_w,    // [81][16][27]
    const float* __restrict__ off_b,    // [81]
    float* __restrict__ out)            // [32][16][128][128]
{
    const int w = threadIdx.x;                 // 0..127
    const int h = blockIdx.x & (HH - 1);       // 0..127
    const int d = blockIdx.x >> 7;             // 0..15

    float outacc[COUT];
#pragma unroll
    for (int o = 0; o < COUT; ++o) outacc[o] = 0.f;

    // Per-dimension tap validity (zero padding of the offset conv).
    bool okz[3], oky[3], okx[3];
#pragma unroll
    for (int i = 0; i < 3; ++i) {
        okz[i] = (unsigned)(d + i - 1) < (unsigned)DD;
        oky[i] = (unsigned)(h + i - 1) < (unsigned)HH;
        okx[i] = (unsigned)(w + i - 1) < (unsigned)WW;
    }

    for (int k = 0; k < KK; ++k) {
        // ---- phase 1: offset conv for channels 3k, 3k+1, 3k+2 ----
        float a0 = 0.f, a1 = 0.f, a2 = 0.f;
        const float* w0 = off_w + (size_t)(k * 3 + 0) * (CIN * KK);
        const float* w1 = off_w + (size_t)(k * 3 + 1) * (CIN * KK);
        const float* w2 = off_w + (size_t)(k * 3 + 2) * (CIN * KK);

        if (TR) {
#pragma unroll
            for (int t = 0; t < 27; ++t) {
                const int tz = t / 9, ty = (t / 3) % 3, tx = t % 3;
                const bool ok = okz[tz] && oky[ty] && okx[tx];
                float cv[16];
                if (ok) {
                    const int vox = ((d + tz - 1) * HH + (h + ty - 1)) * WW + (w + tx - 1);
                    load16(x + (size_t)vox * CIN, cv);
                } else {
#pragma unroll
                    for (int ci = 0; ci < 16; ++ci) cv[ci] = 0.f;
                }
#pragma unroll
                for (int ci = 0; ci < 16; ++ci) {
                    const float v = cv[ci];
                    a0 = fmaf(v, w0[ci * 27 + t], a0);
                    a1 = fmaf(v, w1[ci * 27 + t], a1);
                    a2 = fmaf(v, w2[ci * 27 + t], a2);
                }
            }
        } else {
            for (int ci = 0; ci < CIN; ++ci) {
                const float* xc = x + (size_t)ci * DHW;
#pragma unroll
                for (int t = 0; t < 27; ++t) {
                    const int tz = t / 9, ty = (t / 3) % 3, tx = t % 3;
                    const bool ok = okz[tz] && oky[ty] && okx[tx];
                    const float v = ok ? xc[((d + tz - 1) * HH + (h + ty - 1)) * WW + (w + tx - 1)] : 0.f;
                    a0 = fmaf(v, w0[ci * 27 + t], a0);
                    a1 = fmaf(v, w1[ci * 27 + t], a1);
                    a2 = fmaf(v, w2[ci * 27 + t], a2);
                }
            }
        }

        const float dxo = tanhf(a0 + off_b[k * 3 + 0]) * 4.f;
        const float dyo = tanhf(a1 + off_b[k * 3 + 1]) * 4.f;
        const float dzo = tanhf(a2 + off_b[k * 3 + 2]) * 2.f;

        // ---- phase 2: trilinear sample at the deformed tap ----
        const int rx = k % 3 - 1, ry = (k / 3) % 3 - 1, rz = k / 9 - 1;
        // absolute coords in the padded volume
        const float gx = (float)(w + 1 + rx) + dxo;
        const float gy = (float)(h + 1 + ry) + dyo;
        const float gz = (float)(d + 1 + rz) + dzo;
        const float fx0 = floorf(gx), fy0 = floorf(gy), fz0 = floorf(gz);
        const float fx = gx - fx0, fy = gy - fy0, fz = gz - fz0;
        // corner 0 in ORIGINAL (unpadded) coords; a padded coord p maps to p-1.
        const int x0 = (int)fx0 - 1, y0 = (int)fy0 - 1, z0 = (int)fz0 - 1;

        float samp[CIN];
#pragma unroll
        for (int ci = 0; ci < CIN; ++ci) samp[ci] = 0.f;

#pragma unroll
        for (int c = 0; c < 8; ++c) {
            const int cx = x0 + (c & 1);
            const int cy = y0 + ((c >> 1) & 1);
            const int cz = z0 + (c >> 2);
            const float wt = ((c & 1) ? fx : 1.f - fx) *
                             (((c >> 1) & 1) ? fy : 1.f - fy) *
                             ((c >> 2) ? fz : 1.f - fz);
            if ((unsigned)cx < (unsigned)WW && (unsigned)cy < (unsigned)HH &&
                (unsigned)cz < (unsigned)DD) {
                if (TR) {
                    float cv[16];
                    load16(x + (size_t)(((cz * HH) + cy) * WW + cx) * CIN, cv);
#pragma unroll
                    for (int ci = 0; ci < 16; ++ci) samp[ci] = fmaf(wt, cv[ci], samp[ci]);
                } else {
                    const float* p = x + ((cz * HH) + cy) * WW + cx;
#pragma unroll
                    for (int ci = 0; ci < 16; ++ci) samp[ci] = fmaf(wt, p[(size_t)ci * DHW], samp[ci]);
                }
            }
        }

        // ---- phase 3: contraction with main weight for this k ----
#pragma unroll
        for (int o = 0; o < COUT; ++o) {
            float s = 0.f;
#pragma unroll
            for (int ci = 0; ci < CIN; ++ci)
                s = fmaf(weight[(o * CIN + ci) * KK + k], samp[ci], s);
            outacc[o] += s;
        }
    }

    const int vox = (d * HH + h) * WW + w;
#pragma unroll
    for (int o = 0; o < COUT; ++o)
        out[(size_t)o * DHW + vox] = outacc[o] + bias[o];
}

extern "C" void kernel_launch(void* const* d_in, const int* in_sizes, int n_in,
                              void* d_out, int out_size, void* d_ws, size_t ws_size,
                              hipStream_t stream) {
    const float* x      = (const float*)d_in[0];
    const float* weight = (const float*)d_in[1];
    const float* bias   = (const float*)d_in[2];
    const float* off_w  = (const float*)d_in[3];
    const float* off_b  = (const float*)d_in[4];
    float* out = (float*)d_out;

    const size_t need = (size_t)DHW * CIN * sizeof(float);   // 16 MiB
    if (ws_size >= need) {
        float* xt = (float*)d_ws;
        transpose_x<<<(CIN * DHW + 255) / 256, 256, 0, stream>>>(x, xt);
        deform_fused<true><<<DD * HH, 128, 0, stream>>>(xt, weight, bias, off_w, off_b, out);
    } else {
        deform_fused<false><<<DD * HH, 128, 0, stream>>>(x, weight, bias, off_w, off_b, out);
    }
}

// Round 2
// 1117.547 us; speedup vs baseline: 6.1750x; 6.1750x over previous
//
#include <hip/hip_runtime.h>

#define DD 16
#define HH 128
#define WW 128
#define DHW (DD * HH * WW)   // 262144
#define CIN 16
#define COUT 32
#define KK 27
#define NOFF 81              // 3*KK offset channels

// ---- ws layout (full path) ----
// [0, 140KB)         wA: off_w transposed to [t][ci][j]  (27*16*81 floats)
// [140KB, ~196KB)    wB: weight transposed to [k][o][ci] (27*32*16 floats)
// [256KB, 256KB+16MB) xt: x transposed to [z][y][x][ci]
#define WA_ELEMS (KK * CIN * NOFF)    // 34992
#define WB_ELEMS (KK * COUT * CIN)    // 13824
#define XT_OFF_BYTES (256 * 1024)
#define WS_NEED (XT_OFF_BYTES + (size_t)DHW * CIN * sizeof(float))

__global__ __launch_bounds__(256) void transpose_x(const float* __restrict__ x,
                                                   float* __restrict__ xt) {
    int idx = blockIdx.x * 256 + threadIdx.x;
    if (idx >= CIN * DHW) return;
    int ci = idx >> 18;
    int v  = idx & (DHW - 1);
    xt[(size_t)v * CIN + ci] = x[idx];
}

__global__ __launch_bounds__(256) void transpose_w(const float* __restrict__ off_w,
                                                   const float* __restrict__ weight,
                                                   float* __restrict__ wA,
                                                   float* __restrict__ wB) {
    int idx = blockIdx.x * 256 + threadIdx.x;
    if (idx < WA_ELEMS) {
        int j = idx / (CIN * KK);
        int r = idx % (CIN * KK);
        int ci = r / KK, t = r % KK;
        wA[t * (CIN * NOFF) + ci * NOFF + j] = off_w[idx];
    }
    if (idx < WB_ELEMS) {
        int o = idx / (CIN * KK);
        int r = idx % (CIN * KK);
        int ci = r / KK, k = r % KK;
        wB[k * (COUT * CIN) + o * CIN + ci] = weight[idx];
    }
}

__device__ __forceinline__ void load16(const float* p, float* cv) {
    const float4* q = reinterpret_cast<const float4*>(p);
    float4 a = q[0], b = q[1], c = q[2], d = q[3];
    cv[0] = a.x; cv[1] = a.y; cv[2]  = a.z; cv[3]  = a.w;
    cv[4] = b.x; cv[5] = b.y; cv[6]  = b.z; cv[7]  = b.w;
    cv[8] = c.x; cv[9] = c.y; cv[10] = c.z; cv[11] = c.w;
    cv[12] = d.x; cv[13] = d.y; cv[14] = d.z; cv[15] = d.w;
}

__device__ __forceinline__ float fast_tanh(float s) {
    // tanh(s) = (e-1)/(e+1), e = exp(2s); clamp avoids inf/inf
    float e = __expf(fminf(2.f * s, 80.f));
    return (e - 1.f) * __builtin_amdgcn_rcpf(e + 1.f);
}

// ---------------------------------------------------------------------------
// Fused deformable conv, restructured:
//   phase 1: ALL 81 offset channels in one pass over the 27 neighbors
//   phase 1b: tanh+scale -> LDS (fp16, thread-private, no barrier)
//   phase 2/3: rolled k-loop: trilinear sample + 32x16 contraction
// ---------------------------------------------------------------------------
__global__ __launch_bounds__(128, 3) void deform_full(
    const float* __restrict__ xt,     // [DHW][16]
    const float* __restrict__ wA,     // [27][16][81]
    const float* __restrict__ wB,     // [27][32][16]
    const float* __restrict__ off_b,  // [81]
    const float* __restrict__ bias,   // [32]
    float* __restrict__ out)          // [32][DHW]
{
    __shared__ _Float16 loff[128 * 82];

    const int w = threadIdx.x;
    const int h = blockIdx.x & (HH - 1);
    const int d = blockIdx.x >> 7;

    // ---- phase 1: offset conv, all 81 channels ----
    float a[NOFF];
#pragma unroll
    for (int j = 0; j < NOFF; ++j) a[j] = 0.f;

#pragma unroll 1
    for (int t = 0; t < KK; ++t) {
        const int tz = t / 9, ty = (t / 3) % 3, tx = t % 3;
        const int zz = d + tz - 1, yy = h + ty - 1, xx = w + tx - 1;
        float cv[16];
        if ((unsigned)zz < (unsigned)DD && (unsigned)yy < (unsigned)HH &&
            (unsigned)xx < (unsigned)WW) {
            load16(xt + (size_t)(((zz * HH) + yy) * WW + xx) * CIN, cv);
        } else {
#pragma unroll
            for (int ci = 0; ci < 16; ++ci) cv[ci] = 0.f;
        }
        const float* wt = wA + t * (CIN * NOFF);
#pragma unroll
        for (int ci = 0; ci < 16; ++ci) {
            const float v = cv[ci];
#pragma unroll
            for (int j = 0; j < NOFF; ++j)
                a[j] = fmaf(v, wt[ci * NOFF + j], a[j]);
        }
    }

    // ---- phase 1b: tanh + scale -> LDS fp16 ----
#pragma unroll
    for (int j = 0; j < NOFF; ++j) {
        const float sc = (j % 3 == 2) ? 2.f : 4.f;
        loff[w * 82 + j] = (_Float16)(fast_tanh(a[j] + off_b[j]) * sc);
    }
    // thread-private LDS: no __syncthreads needed

    // ---- phase 2/3: sample + contract ----
    float outacc[COUT];
#pragma unroll
    for (int o = 0; o < COUT; ++o) outacc[o] = 0.f;

#pragma unroll 1
    for (int k = 0; k < KK; ++k) {
        const float dxo = (float)loff[w * 82 + 3 * k + 0];
        const float dyo = (float)loff[w * 82 + 3 * k + 1];
        const float dzo = (float)loff[w * 82 + 3 * k + 2];

        const int rx = k % 3 - 1, ry = (k / 3) % 3 - 1, rz = k / 9 - 1;
        const float gx = (float)(w + 1 + rx) + dxo;
        const float gy = (float)(h + 1 + ry) + dyo;
        const float gz = (float)(d + 1 + rz) + dzo;
        const float fx0 = floorf(gx), fy0 = floorf(gy), fz0 = floorf(gz);
        const float fx = gx - fx0, fy = gy - fy0, fz = gz - fz0;
        const int x0 = (int)fx0 - 1, y0 = (int)fy0 - 1, z0 = (int)fz0 - 1;

        float samp[CIN];
#pragma unroll
        for (int ci = 0; ci < CIN; ++ci) samp[ci] = 0.f;

#pragma unroll
        for (int c = 0; c < 8; ++c) {
            const int cx = x0 + (c & 1);
            const int cy = y0 + ((c >> 1) & 1);
            const int cz = z0 + (c >> 2);
            const float wt = ((c & 1) ? fx : 1.f - fx) *
                             (((c >> 1) & 1) ? fy : 1.f - fy) *
                             ((c >> 2) ? fz : 1.f - fz);
            if ((unsigned)cx < (unsigned)WW && (unsigned)cy < (unsigned)HH &&
                (unsigned)cz < (unsigned)DD) {
                float cv[16];
                load16(xt + (size_t)(((cz * HH) + cy) * WW + cx) * CIN, cv);
#pragma unroll
                for (int ci = 0; ci < 16; ++ci)
                    samp[ci] = fmaf(wt, cv[ci], samp[ci]);
            }
        }

        const float* wk = wB + k * (COUT * CIN);
#pragma unroll
        for (int o = 0; o < COUT; ++o) {
            float s = 0.f;
#pragma unroll
            for (int ci = 0; ci < 16; ++ci)
                s = fmaf(wk[o * CIN + ci], samp[ci], s);
            outacc[o] += s;
        }
    }

    const int vox = (d * HH + h) * WW + w;
#pragma unroll
    for (int o = 0; o < COUT; ++o)
        out[(size_t)o * DHW + vox] = outacc[o] + bias[o];
}

// ---------------------------------------------------------------------------
// Fallback (ws too small): round-1 fused kernel, original x layout.
// ---------------------------------------------------------------------------
__global__ __launch_bounds__(128) void deform_fallback(
    const float* __restrict__ x,
    const float* __restrict__ weight,
    const float* __restrict__ bias,
    const float* __restrict__ off_w,
    const float* __restrict__ off_b,
    float* __restrict__ out)
{
    const int w = threadIdx.x;
    const int h = blockIdx.x & (HH - 1);
    const int d = blockIdx.x >> 7;

    float outacc[COUT];
#pragma unroll
    for (int o = 0; o < COUT; ++o) outacc[o] = 0.f;

    for (int k = 0; k < KK; ++k) {
        float a0 = 0.f, a1 = 0.f, a2 = 0.f;
        const float* w0 = off_w + (size_t)(k * 3 + 0) * (CIN * KK);
        const float* w1 = off_w + (size_t)(k * 3 + 1) * (CIN * KK);
        const float* w2 = off_w + (size_t)(k * 3 + 2) * (CIN * KK);
        for (int ci = 0; ci < CIN; ++ci) {
            const float* xc = x + (size_t)ci * DHW;
#pragma unroll
            for (int t = 0; t < KK; ++t) {
                const int tz = t / 9, ty = (t / 3) % 3, tx = t % 3;
                const int zz = d + tz - 1, yy = h + ty - 1, xx = w + tx - 1;
                const bool ok = (unsigned)zz < (unsigned)DD &&
                                (unsigned)yy < (unsigned)HH &&
                                (unsigned)xx < (unsigned)WW;
                const float v = ok ? xc[((zz)*HH + yy) * WW + xx] : 0.f;
                a0 = fmaf(v, w0[ci * KK + t], a0);
                a1 = fmaf(v, w1[ci * KK + t], a1);
                a2 = fmaf(v, w2[ci * KK + t], a2);
            }
        }
        const float dxo = fast_tanh(a0 + off_b[k * 3 + 0]) * 4.f;
        const float dyo = fast_tanh(a1 + off_b[k * 3 + 1]) * 4.f;
        const float dzo = fast_tanh(a2 + off_b[k * 3 + 2]) * 2.f;

        const int rx = k % 3 - 1, ry = (k / 3) % 3 - 1, rz = k / 9 - 1;
        const float gx = (float)(w + 1 + rx) + dxo;
        const float gy = (float)(h + 1 + ry) + dyo;
        const float gz = (float)(d + 1 + rz) + dzo;
        const float fx0 = floorf(gx), fy0 = floorf(gy), fz0 = floorf(gz);
        const float fx = gx - fx0, fy = gy - fy0, fz = gz - fz0;
        const int x0 = (int)fx0 - 1, y0 = (int)fy0 - 1, z0 = (int)fz0 - 1;

        float samp[CIN];
#pragma unroll
        for (int ci = 0; ci < CIN; ++ci) samp[ci] = 0.f;
#pragma unroll
        for (int c = 0; c < 8; ++c) {
            const int cx = x0 + (c & 1);
            const int cy = y0 + ((c >> 1) & 1);
            const int cz = z0 + (c >> 2);
            const float wt = ((c & 1) ? fx : 1.f - fx) *
                             (((c >> 1) & 1) ? fy : 1.f - fy) *
                             ((c >> 2) ? fz : 1.f - fz);
            if ((unsigned)cx < (unsigned)WW && (unsigned)cy < (unsigned)HH &&
                (unsigned)cz < (unsigned)DD) {
                const float* p = x + ((cz * HH) + cy) * WW + cx;
#pragma unroll
                for (int ci = 0; ci < 16; ++ci)
                    samp[ci] = fmaf(wt, p[(size_t)ci * DHW], samp[ci]);
            }
        }
#pragma unroll
        for (int o = 0; o < COUT; ++o) {
            float s = 0.f;
#pragma unroll
            for (int ci = 0; ci < 16; ++ci)
                s = fmaf(weight[(o * CIN + ci) * KK + k], samp[ci], s);
            outacc[o] += s;
        }
    }
    const int vox = (d * HH + h) * WW + w;
#pragma unroll
    for (int o = 0; o < COUT; ++o)
        out[(size_t)o * DHW + vox] = outacc[o] + bias[o];
}

extern "C" void kernel_launch(void* const* d_in, const int* in_sizes, int n_in,
                              void* d_out, int out_size, void* d_ws, size_t ws_size,
                              hipStream_t stream) {
    const float* x      = (const float*)d_in[0];
    const float* weight = (const float*)d_in[1];
    const float* bias   = (const float*)d_in[2];
    const float* off_w  = (const float*)d_in[3];
    const float* off_b  = (const float*)d_in[4];
    float* out = (float*)d_out;

    if (ws_size >= WS_NEED) {
        float* wAbuf = (float*)d_ws;
        float* wBbuf = wAbuf + WA_ELEMS;
        float* xt    = (float*)((char*)d_ws + XT_OFF_BYTES);
        transpose_w<<<(WA_ELEMS + 255) / 256, 256, 0, stream>>>(off_w, weight, wAbuf, wBbuf);
        transpose_x<<<(CIN * DHW + 255) / 256, 256, 0, stream>>>(x, xt);
        deform_full<<<DD * HH, 128, 0, stream>>>(xt, wAbuf, wBbuf, off_b, bias, out);
    } else {
        deform_fallback<<<DD * HH, 128, 0, stream>>>(x, weight, bias, off_w, off_b, out);
    }
}

// Round 3
// 894.631 us; speedup vs baseline: 7.7136x; 1.2492x over previous
//
#include <hip/hip_runtime.h>

#define DD 16
#define HH 128
#define WW 128
#define DHW (DD * HH * WW)   // 262144
#define CIN 16
#define COUT 32
#define KK 27
#define NOFF 81

typedef _Float16 h2 __attribute__((ext_vector_type(2)));
struct H16 { h2 v[8]; };     // 16 fp16 channels = 32 B

// ---- ws layout ----
// [0, 8MB)          xt: fp16 [vox][16]
// [8MB, +70KB)      wA2: off_w packed pairs [t][p][j]   (27*8*81 h2)
// [next, +28KB)     wB2: weight packed pairs [k][o][p]  (27*32*8 h2)
#define XT_BYTES ((size_t)DHW * CIN * 2)            // 8 MiB
#define WA2_ELEMS (KK * 8 * NOFF)                   // 17496
#define WB2_ELEMS (KK * COUT * 8)                   // 6912
#define WA2_OFF  XT_BYTES
#define WB2_OFF  (WA2_OFF + (size_t)WA2_ELEMS * 4)
#define WS_NEED  (WB2_OFF + (size_t)WB2_ELEMS * 4)

__device__ __forceinline__ float fdot2(h2 a, h2 b, float c) {
#if __has_builtin(__builtin_amdgcn_fdot2)
    return __builtin_amdgcn_fdot2(a, b, c, false);
#else
    return fmaf((float)a[1], (float)b[1], fmaf((float)a[0], (float)b[0], c));
#endif
}

__device__ __forceinline__ float fast_tanh(float s) {
    float e = __expf(fminf(2.f * s, 80.f));
    return (e - 1.f) * __builtin_amdgcn_rcpf(e + 1.f);
}

// x [ci][vox] fp32  ->  xt [vox][ci] fp16
__global__ __launch_bounds__(256) void transpose_x_h(const float* __restrict__ x,
                                                     H16* __restrict__ xt) {
    int vox = blockIdx.x * 256 + threadIdx.x;
    if (vox >= DHW) return;
    H16 o;
#pragma unroll
    for (int p = 0; p < 8; ++p) {
        o.v[p][0] = (_Float16)x[(size_t)(2 * p) * DHW + vox];
        o.v[p][1] = (_Float16)x[(size_t)(2 * p + 1) * DHW + vox];
    }
    xt[vox] = o;
}

// off_w [j][ci][t] -> wA2 [t][p][j] pairs ; weight [o][ci][k] -> wB2 [k][o][p] pairs
__global__ __launch_bounds__(256) void pack_w(const float* __restrict__ off_w,
                                              const float* __restrict__ weight,
                                              h2* __restrict__ wA2,
                                              h2* __restrict__ wB2) {
    int idx = blockIdx.x * 256 + threadIdx.x;
    if (idx < WA2_ELEMS) {
        int t = idx / (8 * NOFF);
        int r = idx % (8 * NOFF);
        int p = r / NOFF, j = r % NOFF;
        h2 v;
        v[0] = (_Float16)off_w[(size_t)(j * CIN + 2 * p) * KK + t];
        v[1] = (_Float16)off_w[(size_t)(j * CIN + 2 * p + 1) * KK + t];
        wA2[idx] = v;
    }
    if (idx < WB2_ELEMS) {
        int k = idx / (COUT * 8);
        int r = idx % (COUT * 8);
        int o = r / 8, p = r % 8;
        h2 v;
        v[0] = (_Float16)weight[(size_t)(o * CIN + 2 * p) * KK + k];
        v[1] = (_Float16)weight[(size_t)(o * CIN + 2 * p + 1) * KK + k];
        wB2[(k * COUT + o) * 8 + p] = v;
    }
}

// ---------------------------------------------------------------------------
// Fused kernel, fp16 data path + dot2/pk_fma, XCD-swizzled blocks.
// ---------------------------------------------------------------------------
__global__ __launch_bounds__(128, 3) void deform_full(
    const H16* __restrict__ xt,       // [DHW] (32B each)
    const h2* __restrict__ wA2,       // [27][8][81]
    const h2* __restrict__ wB2,       // [27][32][8]
    const float* __restrict__ off_b,  // [81]
    const float* __restrict__ bias,   // [32]
    float* __restrict__ out)          // [32][DHW]
{
    __shared__ _Float16 loff[128 * 82];

    // XCD-aware swizzle: 2048 blocks, 8 XCDs, 256 blocks/XCD chunk (bijective).
    const int lb = ((blockIdx.x & 7) << 8) | (blockIdx.x >> 3);
    const int w = threadIdx.x;
    const int h = lb & (HH - 1);
    const int d = lb >> 7;

    // ---- phase 1: offset conv, all 81 channels, dot2 over ci pairs ----
    float a[NOFF];
#pragma unroll
    for (int j = 0; j < NOFF; ++j) a[j] = 0.f;

#pragma unroll 1
    for (int t = 0; t < KK; ++t) {
        const int tz = t / 9, ty = (t / 3) % 3, tx = t % 3;
        const int zz = d + tz - 1, yy = h + ty - 1, xx = w + tx - 1;
        H16 cv;
        if ((unsigned)zz < (unsigned)DD && (unsigned)yy < (unsigned)HH &&
            (unsigned)xx < (unsigned)WW) {
            cv = xt[(size_t)(((zz * HH) + yy) * WW + xx)];
        } else {
#pragma unroll
            for (int p = 0; p < 8; ++p) { cv.v[p][0] = (_Float16)0.f; cv.v[p][1] = (_Float16)0.f; }
        }
        const h2* wt = wA2 + (size_t)t * (8 * NOFF);
#pragma unroll
        for (int p = 0; p < 8; ++p) {
#pragma unroll
            for (int j = 0; j < NOFF; ++j)
                a[j] = fdot2(cv.v[p], wt[p * NOFF + j], a[j]);
        }
    }

    // ---- phase 1b: tanh + scale -> LDS fp16 (thread-private) ----
#pragma unroll
    for (int j = 0; j < NOFF; ++j) {
        const float sc = (j % 3 == 2) ? 2.f : 4.f;
        loff[w * 82 + j] = (_Float16)(fast_tanh(a[j] + off_b[j]) * sc);
    }

    // ---- phase 2/3: trilinear sample (pk_fma) + contraction (dot2) ----
    float outacc[COUT];
#pragma unroll
    for (int o = 0; o < COUT; ++o) outacc[o] = 0.f;

#pragma unroll 1
    for (int k = 0; k < KK; ++k) {
        const float dxo = (float)loff[w * 82 + 3 * k + 0];
        const float dyo = (float)loff[w * 82 + 3 * k + 1];
        const float dzo = (float)loff[w * 82 + 3 * k + 2];

        const int rx = k % 3 - 1, ry = (k / 3) % 3 - 1, rz = k / 9 - 1;
        const float gx = (float)(w + 1 + rx) + dxo;
        const float gy = (float)(h + 1 + ry) + dyo;
        const float gz = (float)(d + 1 + rz) + dzo;
        const float fx0 = floorf(gx), fy0 = floorf(gy), fz0 = floorf(gz);
        const float fx = gx - fx0, fy = gy - fy0, fz = gz - fz0;
        const int x0 = (int)fx0 - 1, y0 = (int)fy0 - 1, z0 = (int)fz0 - 1;

        h2 samp2[8];
#pragma unroll
        for (int p = 0; p < 8; ++p) { samp2[p][0] = (_Float16)0.f; samp2[p][1] = (_Float16)0.f; }

#pragma unroll
        for (int c = 0; c < 8; ++c) {
            const int cx = x0 + (c & 1);
            const int cy = y0 + ((c >> 1) & 1);
            const int cz = z0 + (c >> 2);
            const float wt = ((c & 1) ? fx : 1.f - fx) *
                             (((c >> 1) & 1) ? fy : 1.f - fy) *
                             ((c >> 2) ? fz : 1.f - fz);
            if ((unsigned)cx < (unsigned)WW && (unsigned)cy < (unsigned)HH &&
                (unsigned)cz < (unsigned)DD) {
                H16 cv = xt[(size_t)(((cz * HH) + cy) * WW + cx)];
                const _Float16 wh = (_Float16)wt;
                h2 w2; w2[0] = wh; w2[1] = wh;
#pragma unroll
                for (int p = 0; p < 8; ++p)
                    samp2[p] = samp2[p] + w2 * cv.v[p];   // v_pk_fma/mul+add
            }
        }

        const h2* wk = wB2 + (size_t)k * (COUT * 8);
#pragma unroll
        for (int o = 0; o < COUT; ++o) {
            float s = 0.f;
#pragma unroll
            for (int p = 0; p < 8; ++p)
                s = fdot2(samp2[p], wk[o * 8 + p], s);
            outacc[o] += s;
        }
    }

    const int vox = (d * HH + h) * WW + w;
#pragma unroll
    for (int o = 0; o < COUT; ++o)
        out[(size_t)o * DHW + vox] = outacc[o] + bias[o];
}

// ---------------------------------------------------------------------------
// Fallback (ws too small): fully fp32, original x layout.
// ---------------------------------------------------------------------------
__global__ __launch_bounds__(128) void deform_fallback(
    const float* __restrict__ x,
    const float* __restrict__ weight,
    const float* __restrict__ bias,
    const float* __restrict__ off_w,
    const float* __restrict__ off_b,
    float* __restrict__ out)
{
    const int w = threadIdx.x;
    const int h = blockIdx.x & (HH - 1);
    const int d = blockIdx.x >> 7;

    float outacc[COUT];
#pragma unroll
    for (int o = 0; o < COUT; ++o) outacc[o] = 0.f;

    for (int k = 0; k < KK; ++k) {
        float a0 = 0.f, a1 = 0.f, a2 = 0.f;
        const float* w0 = off_w + (size_t)(k * 3 + 0) * (CIN * KK);
        const float* w1 = off_w + (size_t)(k * 3 + 1) * (CIN * KK);
        const float* w2 = off_w + (size_t)(k * 3 + 2) * (CIN * KK);
        for (int ci = 0; ci < CIN; ++ci) {
            const float* xc = x + (size_t)ci * DHW;
#pragma unroll
            for (int t = 0; t < KK; ++t) {
                const int tz = t / 9, ty = (t / 3) % 3, tx = t % 3;
                const int zz = d + tz - 1, yy = h + ty - 1, xx = w + tx - 1;
                const bool ok = (unsigned)zz < (unsigned)DD &&
                                (unsigned)yy < (unsigned)HH &&
                                (unsigned)xx < (unsigned)WW;
                const float v = ok ? xc[(zz * HH + yy) * WW + xx] : 0.f;
                a0 = fmaf(v, w0[ci * KK + t], a0);
                a1 = fmaf(v, w1[ci * KK + t], a1);
                a2 = fmaf(v, w2[ci * KK + t], a2);
            }
        }
        const float dxo = fast_tanh(a0 + off_b[k * 3 + 0]) * 4.f;
        const float dyo = fast_tanh(a1 + off_b[k * 3 + 1]) * 4.f;
        const float dzo = fast_tanh(a2 + off_b[k * 3 + 2]) * 2.f;

        const int rx = k % 3 - 1, ry = (k / 3) % 3 - 1, rz = k / 9 - 1;
        const float gx = (float)(w + 1 + rx) + dxo;
        const float gy = (float)(h + 1 + ry) + dyo;
        const float gz = (float)(d + 1 + rz) + dzo;
        const float fx0 = floorf(gx), fy0 = floorf(gy), fz0 = floorf(gz);
        const float fx = gx - fx0, fy = gy - fy0, fz = gz - fz0;
        const int x0 = (int)fx0 - 1, y0 = (int)fy0 - 1, z0 = (int)fz0 - 1;

        float samp[CIN];
#pragma unroll
        for (int ci = 0; ci < CIN; ++ci) samp[ci] = 0.f;
#pragma unroll
        for (int c = 0; c < 8; ++c) {
            const int cx = x0 + (c & 1);
            const int cy = y0 + ((c >> 1) & 1);
            const int cz = z0 + (c >> 2);
            const float wt = ((c & 1) ? fx : 1.f - fx) *
                             (((c >> 1) & 1) ? fy : 1.f - fy) *
                             ((c >> 2) ? fz : 1.f - fz);
            if ((unsigned)cx < (unsigned)WW && (unsigned)cy < (unsigned)HH &&
                (unsigned)cz < (unsigned)DD) {
                const float* p = x + ((cz * HH) + cy) * WW + cx;
#pragma unroll
                for (int ci = 0; ci < 16; ++ci)
                    samp[ci] = fmaf(wt, p[(size_t)ci * DHW], samp[ci]);
            }
        }
#pragma unroll
        for (int o = 0; o < COUT; ++o) {
            float s = 0.f;
#pragma unroll
            for (int ci = 0; ci < 16; ++ci)
                s = fmaf(weight[(o * CIN + ci) * KK + k], samp[ci], s);
            outacc[o] += s;
        }
    }
    const int vox = (d * HH + h) * WW + w;
#pragma unroll
    for (int o = 0; o < COUT; ++o)
        out[(size_t)o * DHW + vox] = outacc[o] + bias[o];
}

extern "C" void kernel_launch(void* const* d_in, const int* in_sizes, int n_in,
                              void* d_out, int out_size, void* d_ws, size_t ws_size,
                              hipStream_t stream) {
    const float* x      = (const float*)d_in[0];
    const float* weight = (const float*)d_in[1];
    const float* bias   = (const float*)d_in[2];
    const float* off_w  = (const float*)d_in[3];
    const float* off_b  = (const float*)d_in[4];
    float* out = (float*)d_out;

    if (ws_size >= WS_NEED) {
        H16* xt = (H16*)d_ws;
        h2* wA2 = (h2*)((char*)d_ws + WA2_OFF);
        h2* wB2 = (h2*)((char*)d_ws + WB2_OFF);
        pack_w<<<(WA2_ELEMS + 255) / 256, 256, 0, stream>>>(off_w, weight, wA2, wB2);
        transpose_x_h<<<(DHW + 255) / 256, 256, 0, stream>>>(x, xt);
        deform_full<<<DD * HH, 128, 0, stream>>>(xt, wA2, wB2, off_b, bias, out);
    } else {
        deform_fallback<<<DD * HH, 128, 0, stream>>>(x, weight, bias, off_w, off_b, out);
    }
}

// Round 4
// 242.270 us; speedup vs baseline: 28.4840x; 3.6927x over previous
//
#include <hip/hip_runtime.h>

#define DD 16
#define HH 128
#define WW 128
#define DHW (DD * HH * WW)   // 262144
#define CIN 16
#define COUT 32
#define KK 27
#define NOFF 81
#define NKC 14               // K-chunks of 32 over (t,ci); taps padded 27->28
#define NNT 6                // n-tiles of 16 over 81->96

typedef _Float16 h2    __attribute__((ext_vector_type(2)));
typedef _Float16 f16x8 __attribute__((ext_vector_type(8)));
typedef float    f32x4 __attribute__((ext_vector_type(4)));
struct H16 { h2 v[8]; };     // 16 fp16 channels = 32 B

// ---- ws layout ----
// [0, 8MB)   xt   : fp16 [vox][16]
// [8MB, +84K) wBf : off_w in MFMA B-fragment order [kc][n][lane][8] fp16
// [next,+27K) wB2 : weight packed pairs [k][o][p] h2 (phase-3 contraction)
#define XT_BYTES   ((size_t)DHW * CIN * 2)            // 8 MiB
#define WBF_OFF    XT_BYTES
#define WBF_ELEMS  (NKC * NNT * 64 * 8)               // 43008 halves
#define WB2_OFF    (WBF_OFF + (size_t)WBF_ELEMS * 2)  // 2-byte halves
#define WB2_ELEMS  (KK * COUT * 8)                    // 6912 h2
#define WS_NEED    (WB2_OFF + (size_t)WB2_ELEMS * 4)

__device__ __forceinline__ float fdot2(h2 a, h2 b, float c) {
#if __has_builtin(__builtin_amdgcn_fdot2)
    return __builtin_amdgcn_fdot2(a, b, c, false);
#else
    return fmaf((float)a[1], (float)b[1], fmaf((float)a[0], (float)b[0], c));
#endif
}

__device__ __forceinline__ float fast_tanh(float s) {
    float e = __expf(fminf(2.f * s, 80.f));
    return (e - 1.f) * __builtin_amdgcn_rcpf(e + 1.f);
}

// x [ci][vox] fp32  ->  xt [vox][ci] fp16
__global__ __launch_bounds__(256) void transpose_x_h(const float* __restrict__ x,
                                                     H16* __restrict__ xt) {
    int vox = blockIdx.x * 256 + threadIdx.x;
    if (vox >= DHW) return;
    H16 o;
#pragma unroll
    for (int p = 0; p < 8; ++p) {
        o.v[p][0] = (_Float16)x[(size_t)(2 * p) * DHW + vox];
        o.v[p][1] = (_Float16)x[(size_t)(2 * p + 1) * DHW + vox];
    }
    xt[vox] = o;
}

// Pack off_w into MFMA B-fragment order and weight into h2 pairs.
// wBf element idx = ((kc*NNT+n)*64 + lane)*8 + i:
//   kglob = kc*32 + 8*(lane>>4) + i ; t = 2*kc + ((lane>>4)>>1)
//   ci = ((lane>>4)&1)*8 + i ; j = n*16 + (lane&15)
__global__ __launch_bounds__(256) void pack_w(const float* __restrict__ off_w,
                                              const float* __restrict__ weight,
                                              _Float16* __restrict__ wBf,
                                              h2* __restrict__ wB2) {
    int idx = blockIdx.x * 256 + threadIdx.x;
    if (idx < WBF_ELEMS) {
        int i    = idx & 7;
        int lane = (idx >> 3) & 63;
        int fn   = idx >> 9;            // kc*NNT + n
        int n    = fn % NNT;
        int kc   = fn / NNT;
        int g    = lane >> 4;
        int t    = kc * 2 + (g >> 1);
        int ci   = (g & 1) * 8 + i;
        int j    = n * 16 + (lane & 15);
        float v = 0.f;
        if (t < KK && j < NOFF) v = off_w[(size_t)(j * CIN + ci) * KK + t];
        wBf[idx] = (_Float16)v;
    }
    if (idx < WB2_ELEMS) {
        int k = idx / (COUT * 8);
        int r = idx % (COUT * 8);
        int o = r >> 3, p = r & 7;
        h2 v;
        v[0] = (_Float16)weight[(size_t)(o * CIN + 2 * p) * KK + k];
        v[1] = (_Float16)weight[(size_t)(o * CIN + 2 * p + 1) * KK + k];
        wB2[idx] = v;
    }
}

// ---------------------------------------------------------------------------
// Fused kernel: phase 1 = MFMA implicit-GEMM offset conv, phase 2/3 = gather
// + contraction with branch-free predicated corner loads.
// ---------------------------------------------------------------------------
__global__ __launch_bounds__(128, 3) void deform_full(
    const H16* __restrict__ xt,       // [DHW] 32B
    const f16x8* __restrict__ wBf,    // B fragments
    const h2* __restrict__ wB2,       // [27][32][8]
    const float* __restrict__ off_b,  // [81]
    const float* __restrict__ bias,   // [32]
    float* __restrict__ out)          // [32][DHW]
{
    __shared__ _Float16 loff[128 * 82];

    const int lb = ((blockIdx.x & 7) << 8) | (blockIdx.x >> 3);  // XCD swizzle
    const int w = threadIdx.x;
    const int h = lb & (HH - 1);
    const int d = lb >> 7;
    const int lane = threadIdx.x & 63;
    const int wave = threadIdx.x >> 6;
    const int g = lane >> 4;
    const int col = lane & 15;

    // ---- phase 1: offset conv as implicit GEMM on matrix cores ----
    f32x4 acc[4][NNT];
#pragma unroll
    for (int mi = 0; mi < 4; ++mi)
#pragma unroll
        for (int n = 0; n < NNT; ++n) acc[mi][n] = f32x4{0.f, 0.f, 0.f, 0.f};

    const f16x8* xt16 = (const f16x8*)xt;   // 2 per voxel (8 ch each)

#pragma unroll 1
    for (int kc = 0; kc < NKC; ++kc) {
        const int t  = kc * 2 + (g >> 1);       // per-lane tap
        const int tz = t / 9, ty = (t / 3) % 3, tx = t % 3;
        const int zz = d + tz - 1, yy = h + ty - 1;
        const bool okzy = (t < KK) && ((unsigned)zz < (unsigned)DD) &&
                          ((unsigned)yy < (unsigned)HH);
        const int zc = min(max(zz, 0), DD - 1);
        const int yc = min(max(yy, 0), HH - 1);
        const int rowbase = (zc * HH + yc) * WW;
        const int txm1 = tx - 1;
        const int half = g & 1;

        f16x8 bfr[NNT];
#pragma unroll
        for (int n = 0; n < NNT; ++n) bfr[n] = wBf[(kc * NNT + n) * 64 + lane];

#pragma unroll
        for (int mi = 0; mi < 4; ++mi) {
            const int xx = (wave * 4 + mi) * 16 + col + txm1;
            const bool ok = okzy && ((unsigned)xx < (unsigned)WW);
            const int xc = min(max(xx, 0), WW - 1);
            union { f16x8 v; uint4 u; } au;
            au.v = xt16[(size_t)(rowbase + xc) * 2 + half];
            if (!ok) au.u = make_uint4(0u, 0u, 0u, 0u);
#pragma unroll
            for (int n = 0; n < NNT; ++n)
                acc[mi][n] = __builtin_amdgcn_mfma_f32_16x16x32_f16(
                    au.v, bfr[n], acc[mi][n], 0, 0, 0);
        }
    }

    // ---- phase 1b: +off_b, tanh, scale -> LDS ----
#pragma unroll
    for (int n = 0; n < NNT; ++n) {
        const int j = n * 16 + col;
        if (j < NOFF) {
            const float ob = off_b[j];
            const float sc = (j % 3 == 2) ? 2.f : 4.f;
#pragma unroll
            for (int mi = 0; mi < 4; ++mi) {
#pragma unroll
                for (int r = 0; r < 4; ++r) {
                    const int vl = (wave * 4 + mi) * 16 + g * 4 + r;
                    loff[vl * 82 + j] =
                        (_Float16)(fast_tanh(acc[mi][n][r] + ob) * sc);
                }
            }
        }
    }
    __syncthreads();

    // ---- phase 2/3: predicated gathers + contraction ----
    float outacc[COUT];
#pragma unroll
    for (int o = 0; o < COUT; ++o) outacc[o] = 0.f;

#pragma unroll 1
    for (int k = 0; k < KK; ++k) {
        const float dxo = (float)loff[w * 82 + 3 * k + 0];
        const float dyo = (float)loff[w * 82 + 3 * k + 1];
        const float dzo = (float)loff[w * 82 + 3 * k + 2];

        const int rx = k % 3 - 1, ry = (k / 3) % 3 - 1, rz = k / 9 - 1;
        const float gx = (float)(w + 1 + rx) + dxo;
        const float gy = (float)(h + 1 + ry) + dyo;
        const float gz = (float)(d + 1 + rz) + dzo;
        const float fx0 = floorf(gx), fy0 = floorf(gy), fz0 = floorf(gz);
        const float fx = gx - fx0, fy = gy - fy0, fz = gz - fz0;
        const int x0 = (int)fx0 - 1, y0 = (int)fy0 - 1, z0 = (int)fz0 - 1;
        const float ifx = 1.f - fx, ify = 1.f - fy, ifz = 1.f - fz;

        float cw[8];
        int cidx[8];
#pragma unroll
        for (int c = 0; c < 8; ++c) {
            const int cx = x0 + (c & 1);
            const int cy = y0 + ((c >> 1) & 1);
            const int cz = z0 + (c >> 2);
            const bool ok = (unsigned)cx < (unsigned)WW &&
                            (unsigned)cy < (unsigned)HH &&
                            (unsigned)cz < (unsigned)DD;
            const float wt = ((c & 1) ? fx : ifx) *
                             (((c >> 1) & 1) ? fy : ify) *
                             ((c >> 2) ? fz : ifz);
            cw[c] = ok ? wt : 0.f;
            const int cxc = min(max(cx, 0), WW - 1);
            const int cyc = min(max(cy, 0), HH - 1);
            const int czc = min(max(cz, 0), DD - 1);
            cidx[c] = (czc * HH + cyc) * WW + cxc;
        }

        H16 cv[8];
#pragma unroll
        for (int c = 0; c < 8; ++c) cv[c] = xt[cidx[c]];

        h2 samp2[8];
#pragma unroll
        for (int p = 0; p < 8; ++p) { samp2[p][0] = (_Float16)0.f; samp2[p][1] = (_Float16)0.f; }
#pragma unroll
        for (int c = 0; c < 8; ++c) {
            const _Float16 wh = (_Float16)cw[c];
            h2 w2; w2[0] = wh; w2[1] = wh;
#pragma unroll
            for (int p = 0; p < 8; ++p)
                samp2[p] = samp2[p] + w2 * cv[c].v[p];
        }

        const h2* wk = wB2 + (size_t)k * (COUT * 8);
#pragma unroll
        for (int o = 0; o < COUT; ++o) {
            float s = 0.f;
#pragma unroll
            for (int p = 0; p < 8; ++p)
                s = fdot2(samp2[p], wk[o * 8 + p], s);
            outacc[o] += s;
        }
    }

    const int vox = (d * HH + h) * WW + w;
#pragma unroll
    for (int o = 0; o < COUT; ++o)
        out[(size_t)o * DHW + vox] = outacc[o] + bias[o];
}

// ---------------------------------------------------------------------------
// Fallback (ws too small): fully fp32, original x layout.
// ---------------------------------------------------------------------------
__global__ __launch_bounds__(128) void deform_fallback(
    const float* __restrict__ x,
    const float* __restrict__ weight,
    const float* __restrict__ bias,
    const float* __restrict__ off_w,
    const float* __restrict__ off_b,
    float* __restrict__ out)
{
    const int w = threadIdx.x;
    const int h = blockIdx.x & (HH - 1);
    const int d = blockIdx.x >> 7;

    float outacc[COUT];
#pragma unroll
    for (int o = 0; o < COUT; ++o) outacc[o] = 0.f;

    for (int k = 0; k < KK; ++k) {
        float a0 = 0.f, a1 = 0.f, a2 = 0.f;
        const float* w0 = off_w + (size_t)(k * 3 + 0) * (CIN * KK);
        const float* w1 = off_w + (size_t)(k * 3 + 1) * (CIN * KK);
        const float* w2 = off_w + (size_t)(k * 3 + 2) * (CIN * KK);
        for (int ci = 0; ci < CIN; ++ci) {
            const float* xc = x + (size_t)ci * DHW;
#pragma unroll
            for (int t = 0; t < KK; ++t) {
                const int tz = t / 9, ty = (t / 3) % 3, tx = t % 3;
                const int zz = d + tz - 1, yy = h + ty - 1, xx = w + tx - 1;
                const bool ok = (unsigned)zz < (unsigned)DD &&
                                (unsigned)yy < (unsigned)HH &&
                                (unsigned)xx < (unsigned)WW;
                const float v = ok ? xc[(zz * HH + yy) * WW + xx] : 0.f;
                a0 = fmaf(v, w0[ci * KK + t], a0);
                a1 = fmaf(v, w1[ci * KK + t], a1);
                a2 = fmaf(v, w2[ci * KK + t], a2);
            }
        }
        const float dxo = fast_tanh(a0 + off_b[k * 3 + 0]) * 4.f;
        const float dyo = fast_tanh(a1 + off_b[k * 3 + 1]) * 4.f;
        const float dzo = fast_tanh(a2 + off_b[k * 3 + 2]) * 2.f;

        const int rx = k % 3 - 1, ry = (k / 3) % 3 - 1, rz = k / 9 - 1;
        const float gx = (float)(w + 1 + rx) + dxo;
        const float gy = (float)(h + 1 + ry) + dyo;
        const float gz = (float)(d + 1 + rz) + dzo;
        const float fx0 = floorf(gx), fy0 = floorf(gy), fz0 = floorf(gz);
        const float fx = gx - fx0, fy = gy - fy0, fz = gz - fz0;
        const int x0 = (int)fx0 - 1, y0 = (int)fy0 - 1, z0 = (int)fz0 - 1;

        float samp[CIN];
#pragma unroll
        for (int ci = 0; ci < CIN; ++ci) samp[ci] = 0.f;
#pragma unroll
        for (int c = 0; c < 8; ++c) {
            const int cx = x0 + (c & 1);
            const int cy = y0 + ((c >> 1) & 1);
            const int cz = z0 + (c >> 2);
            const float wt = ((c & 1) ? fx : 1.f - fx) *
                             (((c >> 1) & 1) ? fy : 1.f - fy) *
                             ((c >> 2) ? fz : 1.f - fz);
            if ((unsigned)cx < (unsigned)WW && (unsigned)cy < (unsigned)HH &&
                (unsigned)cz < (unsigned)DD) {
                const float* p = x + ((cz * HH) + cy) * WW + cx;
#pragma unroll
                for (int ci = 0; ci < 16; ++ci)
                    samp[ci] = fmaf(wt, p[(size_t)ci * DHW], samp[ci]);
            }
        }
#pragma unroll
        for (int o = 0; o < COUT; ++o) {
            float s = 0.f;
#pragma unroll
            for (int ci = 0; ci < 16; ++ci)
                s = fmaf(weight[(o * CIN + ci) * KK + k], samp[ci], s);
            outacc[o] += s;
        }
    }
    const int vox = (d * HH + h) * WW + w;
#pragma unroll
    for (int o = 0; o < COUT; ++o)
        out[(size_t)o * DHW + vox] = outacc[o] + bias[o];
}

extern "C" void kernel_launch(void* const* d_in, const int* in_sizes, int n_in,
                              void* d_out, int out_size, void* d_ws, size_t ws_size,
                              hipStream_t stream) {
    const float* x      = (const float*)d_in[0];
    const float* weight = (const float*)d_in[1];
    const float* bias   = (const float*)d_in[2];
    const float* off_w  = (const float*)d_in[3];
    const float* off_b  = (const float*)d_in[4];
    float* out = (float*)d_out;

    if (ws_size >= WS_NEED) {
        H16* xt = (H16*)d_ws;
        _Float16* wBf = (_Float16*)((char*)d_ws + WBF_OFF);
        h2* wB2 = (h2*)((char*)d_ws + WB2_OFF);
        pack_w<<<(WBF_ELEMS + 255) / 256, 256, 0, stream>>>(off_w, weight, wBf, wB2);
        transpose_x_h<<<(DHW + 255) / 256, 256, 0, stream>>>(x, xt);
        deform_full<<<DD * HH, 128, 0, stream>>>(xt, (const f16x8*)wBf, wB2, off_b, bias, out);
    } else {
        deform_fallback<<<DD * HH, 128, 0, stream>>>(x, weight, bias, off_w, off_b, out);
    }
}

// Round 5
// 172.141 us; speedup vs baseline: 40.0882x; 1.4074x over previous
//
#include <hip/hip_runtime.h>

#define DD 16
#define HH 128
#define WW 128
#define DHW (DD * HH * WW)   // 262144
#define CIN 16
#define COUT 32
#define KK 27
#define NOFF 81
#define NKC 14               // K-chunks of 32 over (tap,ci); taps padded 27->28
#define NNT 6                // phase-1 n-tiles of 16 over 81->96

typedef _Float16 h2    __attribute__((ext_vector_type(2)));
typedef _Float16 f16x8 __attribute__((ext_vector_type(8)));
typedef float    f32x4 __attribute__((ext_vector_type(4)));
struct H16 { h2 v[8]; };     // 16 fp16 channels = 32 B

// ---- ws layout ----
// [0, 8MB)    xt  : fp16 [vox][16]
// [8MB,+84K)  wBf : off_w in MFMA B-frag order [kc][n][lane][8]   (phase 1)
// [next,+28K) wW3 : weight in MFMA A-frag order [kc][mo][lane][8] (phase 3)
#define XT_BYTES   ((size_t)DHW * CIN * 2)            // 8 MiB
#define WBF_OFF    XT_BYTES
#define WBF_ELEMS  (NKC * NNT * 64 * 8)               // 43008 halves
#define WW3_OFF    (WBF_OFF + (size_t)WBF_ELEMS * 2)
#define WW3_ELEMS  (NKC * 2 * 64 * 8)                 // 14336 halves
#define WS_NEED    (WW3_OFF + (size_t)WW3_ELEMS * 2)

__device__ __forceinline__ float fast_tanh(float s) {
    float e = __expf(fminf(2.f * s, 80.f));
    return (e - 1.f) * __builtin_amdgcn_rcpf(e + 1.f);
}

// x [ci][vox] fp32  ->  xt [vox][ci] fp16
__global__ __launch_bounds__(256) void transpose_x_h(const float* __restrict__ x,
                                                     H16* __restrict__ xt) {
    int vox = blockIdx.x * 256 + threadIdx.x;
    if (vox >= DHW) return;
    H16 o;
#pragma unroll
    for (int p = 0; p < 8; ++p) {
        o.v[p][0] = (_Float16)x[(size_t)(2 * p) * DHW + vox];
        o.v[p][1] = (_Float16)x[(size_t)(2 * p + 1) * DHW + vox];
    }
    xt[vox] = o;
}

// Pack off_w into phase-1 B fragments and weight into phase-3 A fragments.
// Both use the 16x16x32 per-lane mapping: idx16 = lane&15, k = 8*(lane>>4)+i,
// with k -> (tap = base + (k>>4), ci = k&15).
__global__ __launch_bounds__(256) void pack_w(const float* __restrict__ off_w,
                                              const float* __restrict__ weight,
                                              _Float16* __restrict__ wBf,
                                              _Float16* __restrict__ wW3) {
    int idx = blockIdx.x * 256 + threadIdx.x;
    if (idx < WBF_ELEMS) {
        int i    = idx & 7;
        int lane = (idx >> 3) & 63;
        int fn   = idx >> 9;            // kc*NNT + n
        int n    = fn % NNT;
        int kc   = fn / NNT;
        int g    = lane >> 4;
        int t    = kc * 2 + (g >> 1);
        int ci   = (g & 1) * 8 + i;
        int j    = n * 16 + (lane & 15);
        float v = 0.f;
        if (t < KK && j < NOFF) v = off_w[(size_t)(j * CIN + ci) * KK + t];
        wBf[idx] = (_Float16)v;
    }
    if (idx < WW3_ELEMS) {
        int i    = idx & 7;
        int lane = (idx >> 3) & 63;
        int fm   = idx >> 9;            // kc*2 + mo
        int mo   = fm & 1;
        int kc   = fm >> 1;
        int g    = lane >> 4;
        int t    = kc * 2 + (g >> 1);
        int ci   = (g & 1) * 8 + i;
        int o    = mo * 16 + (lane & 15);
        float v = 0.f;
        if (t < KK) v = weight[(size_t)(o * CIN + ci) * KK + t];
        wW3[idx] = (_Float16)v;
    }
}

// ---------------------------------------------------------------------------
// Fused kernel: phase 1 = MFMA implicit-GEMM offset conv; phase 2/3 = per-lane
// trilinear sampling directly in MFMA B-fragment layout + MFMA contraction.
// ---------------------------------------------------------------------------
__global__ __launch_bounds__(128, 3) void deform_full(
    const f16x8* __restrict__ xt16,   // 2 per voxel (8 ch each)
    const f16x8* __restrict__ wBf,    // phase-1 B fragments
    const f16x8* __restrict__ wW3,    // phase-3 A fragments
    const float* __restrict__ off_b,  // [81]
    const float* __restrict__ bias,   // [32]
    float* __restrict__ out)          // [32][DHW]
{
    // offsets: [local w][tap*3+comp] fp16, row stride 84 halves (168B, 2-way banks)
    __shared__ _Float16 loff[128 * 84];

    const int lb = ((blockIdx.x & 7) << 8) | (blockIdx.x >> 3);  // XCD swizzle
    const int h = lb & (HH - 1);
    const int d = lb >> 7;
    const int lane = threadIdx.x & 63;
    const int wave = threadIdx.x >> 6;
    const int g = lane >> 4;
    const int col = lane & 15;

    // ---- phase 1: offset conv as implicit GEMM ----
    f32x4 acc[4][NNT];
#pragma unroll
    for (int mi = 0; mi < 4; ++mi)
#pragma unroll
        for (int n = 0; n < NNT; ++n) acc[mi][n] = f32x4{0.f, 0.f, 0.f, 0.f};

#pragma unroll 1
    for (int kc = 0; kc < NKC; ++kc) {
        const int t  = kc * 2 + (g >> 1);
        const int tz = t / 9, ty = (t / 3) % 3, tx = t % 3;
        const int zz = d + tz - 1, yy = h + ty - 1;
        const bool okzy = (t < KK) && ((unsigned)zz < (unsigned)DD) &&
                          ((unsigned)yy < (unsigned)HH);
        const int zc = min(max(zz, 0), DD - 1);
        const int yc = min(max(yy, 0), HH - 1);
        const int rowbase = (zc * HH + yc) * WW;
        const int txm1 = tx - 1;
        const int half = g & 1;

        f16x8 bfr[NNT];
#pragma unroll
        for (int n = 0; n < NNT; ++n) bfr[n] = wBf[(kc * NNT + n) * 64 + lane];

#pragma unroll
        for (int mi = 0; mi < 4; ++mi) {
            const int xx = (wave * 4 + mi) * 16 + col + txm1;
            const bool ok = okzy && ((unsigned)xx < (unsigned)WW);
            const int xc = min(max(xx, 0), WW - 1);
            union { f16x8 v; uint4 u; } au;
            au.v = xt16[(size_t)(rowbase + xc) * 2 + half];
            if (!ok) au.u = make_uint4(0u, 0u, 0u, 0u);
#pragma unroll
            for (int n = 0; n < NNT; ++n)
                acc[mi][n] = __builtin_amdgcn_mfma_f32_16x16x32_f16(
                    au.v, bfr[n], acc[mi][n], 0, 0, 0);
        }
    }

    // ---- phase 1b: +off_b, tanh, scale -> LDS ----
#pragma unroll
    for (int n = 0; n < NNT; ++n) {
        const int j = n * 16 + col;
        if (j < NOFF) {
            const float ob = off_b[j];
            const float sc = (j % 3 == 2) ? 2.f : 4.f;
#pragma unroll
            for (int mi = 0; mi < 4; ++mi) {
#pragma unroll
                for (int r = 0; r < 4; ++r) {
                    const int vl = (wave * 4 + mi) * 16 + g * 4 + r;
                    loff[vl * 84 + j] =
                        (_Float16)(fast_tanh(acc[mi][n][r] + ob) * sc);
                }
            }
        }
    }
    __syncthreads();

    // ---- phase 2/3: sample in B-fragment layout + MFMA contraction ----
    // GEMM: out[o][vox] = sum_{tap,ci} weight[o][ci][tap] * samp[vox][tap][ci]
    f32x4 acc3[2][4];
#pragma unroll
    for (int mo = 0; mo < 2; ++mo)
#pragma unroll
        for (int nv = 0; nv < 4; ++nv) acc3[mo][nv] = f32x4{0.f, 0.f, 0.f, 0.f};

    const int half = g & 1;

#pragma unroll 1
    for (int kc = 0; kc < NKC; ++kc) {
        const int myTap = kc * 2 + (g >> 1);
        const bool tapValid = myTap < KK;
        const int tA = tapValid ? myTap : 0;

        const f16x8 aw0 = wW3[(kc * 2 + 0) * 64 + lane];
        const f16x8 aw1 = wW3[(kc * 2 + 1) * 64 + lane];

        const int rx = tA % 3 - 1, ry = (tA / 3) % 3 - 1, rz = tA / 9 - 1;

#pragma unroll
        for (int nv = 0; nv < 4; ++nv) {
            const int wv = wave * 64 + nv * 16 + col;   // local w of my column

            float dxo = 0.f, dyo = 0.f, dzo = 0.f;
            if (tapValid) {
                dxo = (float)loff[wv * 84 + tA * 3 + 0];
                dyo = (float)loff[wv * 84 + tA * 3 + 1];
                dzo = (float)loff[wv * 84 + tA * 3 + 2];
            }

            const float gx = (float)(wv + 1 + rx) + dxo;
            const float gy = (float)(h + 1 + ry) + dyo;
            const float gz = (float)(d + 1 + rz) + dzo;
            const float fx0 = floorf(gx), fy0 = floorf(gy), fz0 = floorf(gz);
            const float fx = gx - fx0, fy = gy - fy0, fz = gz - fz0;
            const int x0 = (int)fx0 - 1, y0 = (int)fy0 - 1, z0 = (int)fz0 - 1;
            const float ifx = 1.f - fx, ify = 1.f - fy, ifz = 1.f - fz;

            float cw[8];
            int cidx[8];
#pragma unroll
            for (int c = 0; c < 8; ++c) {
                const int cx = x0 + (c & 1);
                const int cy = y0 + ((c >> 1) & 1);
                const int cz = z0 + (c >> 2);
                const bool ok = tapValid &&
                                (unsigned)cx < (unsigned)WW &&
                                (unsigned)cy < (unsigned)HH &&
                                (unsigned)cz < (unsigned)DD;
                const float wt = ((c & 1) ? fx : ifx) *
                                 (((c >> 1) & 1) ? fy : ify) *
                                 ((c >> 2) ? fz : ifz);
                cw[c] = ok ? wt : 0.f;
                const int cxc = min(max(cx, 0), WW - 1);
                const int cyc = min(max(cy, 0), HH - 1);
                const int czc = min(max(cz, 0), DD - 1);
                cidx[c] = (czc * HH + cyc) * WW + cxc;
            }

            f16x8 cv[8];
#pragma unroll
            for (int c = 0; c < 8; ++c)
                cv[c] = xt16[(size_t)cidx[c] * 2 + half];

            union { f16x8 v; h2 s[4]; } sf;
#pragma unroll
            for (int p = 0; p < 4; ++p) { sf.s[p][0] = (_Float16)0.f; sf.s[p][1] = (_Float16)0.f; }
#pragma unroll
            for (int c = 0; c < 8; ++c) {
                const _Float16 wh = (_Float16)cw[c];
                h2 w2; w2[0] = wh; w2[1] = wh;
                const h2* cvp = (const h2*)&cv[c];
#pragma unroll
                for (int p = 0; p < 4; ++p)
                    sf.s[p] = sf.s[p] + w2 * cvp[p];
            }

            acc3[0][nv] = __builtin_amdgcn_mfma_f32_16x16x32_f16(
                aw0, sf.v, acc3[0][nv], 0, 0, 0);
            acc3[1][nv] = __builtin_amdgcn_mfma_f32_16x16x32_f16(
                aw1, sf.v, acc3[1][nv], 0, 0, 0);
        }
    }

    // ---- store: D row = o-in-tile (4g+r), col = vox (16-lane contiguous) ----
    const int rowBase = (d * HH + h) * WW;
#pragma unroll
    for (int mo = 0; mo < 2; ++mo) {
#pragma unroll
        for (int r = 0; r < 4; ++r) {
            const int o = mo * 16 + 4 * g + r;
            const float b = bias[o];
#pragma unroll
            for (int nv = 0; nv < 4; ++nv) {
                const int wv = wave * 64 + nv * 16 + col;
                out[(size_t)o * DHW + rowBase + wv] = acc3[mo][nv][r] + b;
            }
        }
    }
}

// ---------------------------------------------------------------------------
// Fallback (ws too small): fully fp32, original x layout.
// ---------------------------------------------------------------------------
__global__ __launch_bounds__(128) void deform_fallback(
    const float* __restrict__ x,
    const float* __restrict__ weight,
    const float* __restrict__ bias,
    const float* __restrict__ off_w,
    const float* __restrict__ off_b,
    float* __restrict__ out)
{
    const int w = threadIdx.x;
    const int h = blockIdx.x & (HH - 1);
    const int d = blockIdx.x >> 7;

    float outacc[COUT];
#pragma unroll
    for (int o = 0; o < COUT; ++o) outacc[o] = 0.f;

    for (int k = 0; k < KK; ++k) {
        float a0 = 0.f, a1 = 0.f, a2 = 0.f;
        const float* w0 = off_w + (size_t)(k * 3 + 0) * (CIN * KK);
        const float* w1 = off_w + (size_t)(k * 3 + 1) * (CIN * KK);
        const float* w2 = off_w + (size_t)(k * 3 + 2) * (CIN * KK);
        for (int ci = 0; ci < CIN; ++ci) {
            const float* xc = x + (size_t)ci * DHW;
#pragma unroll
            for (int t = 0; t < KK; ++t) {
                const int tz = t / 9, ty = (t / 3) % 3, tx = t % 3;
                const int zz = d + tz - 1, yy = h + ty - 1, xx = w + tx - 1;
                const bool ok = (unsigned)zz < (unsigned)DD &&
                                (unsigned)yy < (unsigned)HH &&
                                (unsigned)xx < (unsigned)WW;
                const float v = ok ? xc[(zz * HH + yy) * WW + xx] : 0.f;
                a0 = fmaf(v, w0[ci * KK + t], a0);
                a1 = fmaf(v, w1[ci * KK + t], a1);
                a2 = fmaf(v, w2[ci * KK + t], a2);
            }
        }
        const float dxo = fast_tanh(a0 + off_b[k * 3 + 0]) * 4.f;
        const float dyo = fast_tanh(a1 + off_b[k * 3 + 1]) * 4.f;
        const float dzo = fast_tanh(a2 + off_b[k * 3 + 2]) * 2.f;

        const int rx = k % 3 - 1, ry = (k / 3) % 3 - 1, rz = k / 9 - 1;
        const float gx = (float)(w + 1 + rx) + dxo;
        const float gy = (float)(h + 1 + ry) + dyo;
        const float gz = (float)(d + 1 + rz) + dzo;
        const float fx0 = floorf(gx), fy0 = floorf(gy), fz0 = floorf(gz);
        const float fx = gx - fx0, fy = gy - fy0, fz = gz - fz0;
        const int x0 = (int)fx0 - 1, y0 = (int)fy0 - 1, z0 = (int)fz0 - 1;

        float samp[CIN];
#pragma unroll
        for (int ci = 0; ci < CIN; ++ci) samp[ci] = 0.f;
#pragma unroll
        for (int c = 0; c < 8; ++c) {
            const int cx = x0 + (c & 1);
            const int cy = y0 + ((c >> 1) & 1);
            const int cz = z0 + (c >> 2);
            const float wt = ((c & 1) ? fx : 1.f - fx) *
                             (((c >> 1) & 1) ? fy : 1.f - fy) *
                             ((c >> 2) ? fz : 1.f - fz);
            if ((unsigned)cx < (unsigned)WW && (unsigned)cy < (unsigned)HH &&
                (unsigned)cz < (unsigned)DD) {
                const float* p = x + ((cz * HH) + cy) * WW + cx;
#pragma unroll
                for (int ci = 0; ci < 16; ++ci)
                    samp[ci] = fmaf(wt, p[(size_t)ci * DHW], samp[ci]);
            }
        }
#pragma unroll
        for (int o = 0; o < COUT; ++o) {
            float s = 0.f;
#pragma unroll
            for (int ci = 0; ci < 16; ++ci)
                s = fmaf(weight[(o * CIN + ci) * KK + k], samp[ci], s);
            outacc[o] += s;
        }
    }
    const int vox = (d * HH + h) * WW + w;
#pragma unroll
    for (int o = 0; o < COUT; ++o)
        out[(size_t)o * DHW + vox] = outacc[o] + bias[o];
}

extern "C" void kernel_launch(void* const* d_in, const int* in_sizes, int n_in,
                              void* d_out, int out_size, void* d_ws, size_t ws_size,
                              hipStream_t stream) {
    const float* x      = (const float*)d_in[0];
    const float* weight = (const float*)d_in[1];
    const float* bias   = (const float*)d_in[2];
    const float* off_w  = (const float*)d_in[3];
    const float* off_b  = (const float*)d_in[4];
    float* out = (float*)d_out;

    if (ws_size >= WS_NEED) {
        H16* xt = (H16*)d_ws;
        _Float16* wBf = (_Float16*)((char*)d_ws + WBF_OFF);
        _Float16* wW3 = (_Float16*)((char*)d_ws + WW3_OFF);
        pack_w<<<(WBF_ELEMS + 255) / 256, 256, 0, stream>>>(off_w, weight, wBf, wW3);
        transpose_x_h<<<(DHW + 255) / 256, 256, 0, stream>>>(x, xt);
        deform_full<<<DD * HH, 128, 0, stream>>>((const f16x8*)xt, (const f16x8*)wBf,
                                                 (const f16x8*)wW3, off_b, bias, out);
    } else {
        deform_fallback<<<DD * HH, 128, 0, stream>>>(x, weight, bias, off_w, off_b, out);
    }
}